// Round 1
// 409.696 us; speedup vs baseline: 1.0145x; 1.0145x over previous
//
#include <hip/hip_runtime.h>
#include <hip/hip_bf16.h>

#define NN 8192
#define FIN 256
#define FOUT 64

typedef int iv4 __attribute__((ext_vector_type(4)));

// K1: Wh = H@W + bW; s = Wh.a1 + a_b; t = Wh.a2; exps + interleaved PP=(e^t, e^.01t).
__global__ __launch_bounds__(256) void k1_proj(
    const float* __restrict__ H, const float* __restrict__ W,
    const float* __restrict__ bW, const float* __restrict__ aw,
    const float* __restrict__ ab,
    float* __restrict__ Wh, float* __restrict__ s_src, float* __restrict__ t_tar,
    float* __restrict__ E1, float* __restrict__ E2, float* __restrict__ PP)
{
    __shared__ float Hs[16 * FIN];
    int tid = threadIdx.x;
    int i0 = blockIdx.x * 16;
    const float4* Hv = (const float4*)(H + (size_t)i0 * FIN);
    float4* Hsv = (float4*)Hs;
    for (int idx = tid; idx < 16 * FIN / 4; idx += 256) Hsv[idx] = Hv[idx];
    __syncthreads();
    int f = tid & 63, sub = tid >> 6;
    float a1f = aw[f], a2f = aw[64 + f];
    float b = bW[f];
    float acc0 = b, acc1 = b, acc2 = b, acc3 = b;
    for (int k = 0; k < FIN; ++k) {
        float w = W[k * FOUT + f];
        acc0 += Hs[(sub     ) * FIN + k] * w;
        acc1 += Hs[(sub +  4) * FIN + k] * w;
        acc2 += Hs[(sub +  8) * FIN + k] * w;
        acc3 += Hs[(sub + 12) * FIN + k] * w;
    }
    float accs[4] = {acc0, acc1, acc2, acc3};
    #pragma unroll
    for (int q = 0; q < 4; ++q) {
        int i = i0 + sub + 4 * q;
        float a = accs[q];
        Wh[(size_t)i * FOUT + f] = a;
        float v1 = a * a1f, v2 = a * a2f;
        #pragma unroll
        for (int o = 32; o > 0; o >>= 1) {
            v1 += __shfl_xor(v1, o);
            v2 += __shfl_xor(v2, o);
        }
        if (f == 0) {
            float s = v1 + ab[0];
            float t = v2;
            s_src[i] = s; t_tar[i] = t;
            E1[i] = __expf(s); E2[i] = __expf(0.01f * s);
            PP[2 * i]     = __expf(t);
            PP[2 * i + 1] = __expf(0.01f * t);
        }
    }
}

// K2 v3: each wave ranks TWO nodes per Ts[k] read (amortizes LDS reads + staging).
// 1024 blocks x 256 threads; block handles 8 g's (4 waves x 2).
__global__ __launch_bounds__(256) void k2_rank(
    const float* __restrict__ t_tar, const float* __restrict__ s_src,
    int* __restrict__ sorted_idx, int* __restrict__ kidx)
{
    __shared__ float Ts[NN];
    int tid = threadIdx.x;
    const float4* tv = (const float4*)t_tar;
    float4* Tsv = (float4*)Ts;
    for (int idx = tid; idx < NN / 4; idx += 256) Tsv[idx] = tv[idx];
    __syncthreads();
    int wv = tid >> 6, lane = tid & 63;
    int gA = blockIdx.x * 8 + wv * 2;
    int gB = gA + 1;
    float tjA = Ts[gA], tjB = Ts[gB];
    float thrA = -s_src[gA], thrB = -s_src[gB];
    int rA = 0, kA = 0, rB = 0, kB = 0;
    #pragma unroll 4
    for (int k = lane; k < NN; k += 64) {
        float tk = Ts[k];
        rA += (tk < tjA || (tk == tjA && k < gA)) ? 1 : 0;
        kA += (tk < thrA) ? 1 : 0;
        rB += (tk < tjB || (tk == tjB && k < gB)) ? 1 : 0;
        kB += (tk < thrB) ? 1 : 0;
    }
    #pragma unroll
    for (int o = 32; o > 0; o >>= 1) {
        rA += __shfl_xor(rA, o); kA += __shfl_xor(kA, o);
        rB += __shfl_xor(rB, o); kB += __shfl_xor(kB, o);
    }
    if (lane == 0) {
        sorted_idx[rA] = gA; kidx[gA] = kA;
        sorted_idx[rB] = gB; kidx[gB] = kB;
    }
}

// K3 phase A: per-chunk (32 m's) totals of v1 = P1*Wh and v2 = P2*Wh in sorted order.
__global__ __launch_bounds__(64) void k3a_tots(
    const float* __restrict__ Wh, const float* __restrict__ PP,
    const int* __restrict__ sorted_idx,
    float* __restrict__ tots1, float* __restrict__ tots2)
{
    int c = blockIdx.x, f = threadIdx.x;
    float t1 = 0.f, t2 = 0.f;
    int m0 = c * 32;
    #pragma unroll 8
    for (int m = m0; m < m0 + 32; ++m) {
        int sj = sorted_idx[m];
        float wh = Wh[(size_t)sj * 64 + f];
        t1 += PP[2 * sj]     * wh;
        t2 += PP[2 * sj + 1] * wh;
    }
    tots1[c * 64 + f] = t1; tots2[c * 64 + f] = t2;
}

// K3 phase BC fused: each block computes its own chunk offsets (linear sum over
// chunk totals, fully parallel across 256 blocks — no single-block scan kernel)
// then emits pre2/suf1 for its chunk.
__global__ __launch_bounds__(64) void k3bc_emit(
    const float* __restrict__ Wh, const float* __restrict__ PP,
    const int* __restrict__ sorted_idx,
    const float* __restrict__ tots1, const float* __restrict__ tots2,
    float* __restrict__ pre2, float* __restrict__ suf1)
{
    int c = blockIdx.x, f = threadIdx.x;
    float o2 = 0.f;
    #pragma unroll 8
    for (int w = 0; w < c; ++w) o2 += tots2[w * 64 + f];
    float o1 = 0.f;
    #pragma unroll 8
    for (int w = c + 1; w < 256; ++w) o1 += tots1[w * 64 + f];
    int m0 = c * 32;
    float whr[32], p1r[32], p2r[32];
    #pragma unroll
    for (int q = 0; q < 32; ++q) {
        int sj = sorted_idx[m0 + q];
        whr[q] = Wh[(size_t)sj * 64 + f];
        p1r[q] = PP[2 * sj]; p2r[q] = PP[2 * sj + 1];
    }
    float run2 = o2;
    #pragma unroll
    for (int q = 0; q < 32; ++q) {
        pre2[(size_t)(m0 + q) * 64 + f] = run2;
        run2 += p2r[q] * whr[q];
    }
    if (c == 255) pre2[(size_t)NN * 64 + f] = run2;   // full prefix total
    float run1 = o1;
    #pragma unroll
    for (int q = 31; q >= 0; --q) {
        run1 += p1r[q] * whr[q];
        suf1[(size_t)(m0 + q) * 64 + f] = run1;
    }
    if (c == 255) suf1[(size_t)NN * 64 + f] = 0.f;
}

// K4+K5 fused: denom[i] = E1_i * S_{adj, cond} P1_j + E2_i * S_{adj, !cond} P2_j
// (cond = s_i + t_j >= 0  <=>  E1_i * P1_j >= 1), streaming A (268 MB, read-once,
// nontemporal) — then the same block emits out for its 8 rows from suf1/pre2.
__global__ __launch_bounds__(256) void k45_denom_out(
    const int* __restrict__ A, const float* __restrict__ PP,
    const float* __restrict__ E1, const float* __restrict__ E2,
    const float* __restrict__ suf1, const float* __restrict__ pre2,
    const int* __restrict__ kidx, float* __restrict__ out)
{
    int tid = threadIdx.x;
    int i0 = blockIdx.x * 8;
    float e1r[8], accA[8], accB[8];
    #pragma unroll
    for (int r = 0; r < 8; ++r) { e1r[r] = E1[i0 + r]; accA[r] = 0.f; accB[r] = 0.f; }
    const float4* PPv = (const float4*)PP;
    for (int jv = tid; jv < NN / 4; jv += 256) {
        float4 ppA = PPv[2 * jv];
        float4 ppB = PPv[2 * jv + 1];
        #pragma unroll
        for (int r = 0; r < 8; ++r) {
            const iv4 a4 = __builtin_nontemporal_load(
                (const iv4*)(A + (size_t)(i0 + r) * NN + jv * 4));
            float e1 = e1r[r];
            {
                bool c = e1 * ppA.x >= 1.0f;
                float af = (float)a4.x;
                accA[r] += af * (c ? ppA.x : 0.0f);
                accB[r] += af * (c ? 0.0f : ppA.y);
            }
            {
                bool c = e1 * ppA.z >= 1.0f;
                float af = (float)a4.y;
                accA[r] += af * (c ? ppA.z : 0.0f);
                accB[r] += af * (c ? 0.0f : ppA.w);
            }
            {
                bool c = e1 * ppB.x >= 1.0f;
                float af = (float)a4.z;
                accA[r] += af * (c ? ppB.x : 0.0f);
                accB[r] += af * (c ? 0.0f : ppB.y);
            }
            {
                bool c = e1 * ppB.z >= 1.0f;
                float af = (float)a4.w;
                accA[r] += af * (c ? ppB.z : 0.0f);
                accB[r] += af * (c ? 0.0f : ppB.w);
            }
        }
    }
    #pragma unroll
    for (int r = 0; r < 8; ++r) {
        #pragma unroll
        for (int o = 32; o > 0; o >>= 1) {
            accA[r] += __shfl_xor(accA[r], o);
            accB[r] += __shfl_xor(accB[r], o);
        }
    }
    __shared__ float red[4][8][2];
    __shared__ float sden[8];
    int wv = tid >> 6;
    if ((tid & 63) == 0) {
        #pragma unroll
        for (int r = 0; r < 8; ++r) { red[wv][r][0] = accA[r]; red[wv][r][1] = accB[r]; }
    }
    __syncthreads();
    if (tid < 8) {
        float sA = red[0][tid][0] + red[1][tid][0] + red[2][tid][0] + red[3][tid][0];
        float sB = red[0][tid][1] + red[1][tid][1] + red[2][tid][1] + red[3][tid][1];
        sden[tid] = E1[i0 + tid] * sA + E2[i0 + tid] * sB;
    }
    __syncthreads();
    int f = tid & 63, sub = tid >> 6;
    #pragma unroll
    for (int rr = 0; rr < 2; ++rr) {
        int r = sub + 4 * rr;
        int i = i0 + r;
        int k = kidx[i];
        float num = E1[i] * suf1[(size_t)k * 64 + f] + E2[i] * pre2[(size_t)k * 64 + f];
        float x = num / sden[r];
        out[(size_t)i * 64 + f] = 1.0f / (1.0f + __expf(-x));
    }
}

extern "C" void kernel_launch(void* const* d_in, const int* in_sizes, int n_in,
                              void* d_out, int out_size, void* d_ws, size_t ws_size,
                              hipStream_t stream) {
    const float* H  = (const float*)d_in[0];
    const int*   A  = (const int*)d_in[1];
    const float* W  = (const float*)d_in[2];
    const float* bW = (const float*)d_in[3];
    const float* aw = (const float*)d_in[4];
    const float* ab = (const float*)d_in[5];
    float* out = (float*)d_out;

    float* ws    = (float*)d_ws;
    float* Wh    = ws;                    // 524288
    float* s_src = Wh + 524288;           // 8192
    float* t_tar = s_src + 8192;          // 8192
    float* E1    = t_tar + 8192;          // 8192
    float* E2    = E1 + 8192;             // 8192
    float* PP    = E2 + 8192;             // 16384
    float* pre2  = PP + 16384;            // 524352 ((N+1)*64)
    float* suf1  = pre2 + 524352;         // 524352
    float* tots1 = suf1 + 524352;         // 16384 (256*64)
    float* tots2 = tots1 + 16384;         // 16384
    int* sorted_idx = (int*)(tots2 + 16384);  // 8192 ints
    int* kidx       = sorted_idx + 8192;      // 8192 ints

    hipLaunchKernelGGL(k1_proj, dim3(512), dim3(256), 0, stream,
                       H, W, bW, aw, ab, Wh, s_src, t_tar, E1, E2, PP);
    hipLaunchKernelGGL(k2_rank, dim3(1024), dim3(256), 0, stream,
                       t_tar, s_src, sorted_idx, kidx);
    hipLaunchKernelGGL(k3a_tots, dim3(256), dim3(64), 0, stream,
                       Wh, PP, sorted_idx, tots1, tots2);
    hipLaunchKernelGGL(k3bc_emit, dim3(256), dim3(64), 0, stream,
                       Wh, PP, sorted_idx, tots1, tots2, pre2, suf1);
    hipLaunchKernelGGL(k45_denom_out, dim3(1024), dim3(256), 0, stream,
                       A, PP, E1, E2, suf1, pre2, kidx, out);
}

// Round 3
// 409.256 us; speedup vs baseline: 1.0156x; 1.0011x over previous
//
#include <hip/hip_runtime.h>

#define NN 8192
#define FIN 256
#define FOUT 64
#define NRANK 256   // blocks that also do the rank phase before joining the A-stream
#define NBLK 1024
#define NUNITS 1024 // A-stream work units (8 rows each)

typedef int iv4 __attribute__((ext_vector_type(4)));

// K1: Wh = H@W + bW; s = Wh.a1 + a_b; t = Wh.a2; exps + interleaved PP=(e^t, e^.01t).
// Also zeroes the dynamic-work counter for kA.
__global__ __launch_bounds__(256) void k1_proj(
    const float* __restrict__ H, const float* __restrict__ W,
    const float* __restrict__ bW, const float* __restrict__ aw,
    const float* __restrict__ ab,
    float* __restrict__ Wh, float* __restrict__ s_src, float* __restrict__ t_tar,
    float* __restrict__ E1, float* __restrict__ E2, float* __restrict__ PP,
    unsigned* __restrict__ ctrs)
{
    __shared__ float Hs[16 * FIN];
    int tid = threadIdx.x;
    if (blockIdx.x == 0 && tid < 4) ctrs[tid] = 0u;
    int i0 = blockIdx.x * 16;
    const float4* Hv = (const float4*)(H + (size_t)i0 * FIN);
    float4* Hsv = (float4*)Hs;
    for (int idx = tid; idx < 16 * FIN / 4; idx += 256) Hsv[idx] = Hv[idx];
    __syncthreads();
    int f = tid & 63, sub = tid >> 6;
    float a1f = aw[f], a2f = aw[64 + f];
    float b = bW[f];
    float acc0 = b, acc1 = b, acc2 = b, acc3 = b;
    for (int k = 0; k < FIN; ++k) {
        float w = W[k * FOUT + f];
        acc0 += Hs[(sub     ) * FIN + k] * w;
        acc1 += Hs[(sub +  4) * FIN + k] * w;
        acc2 += Hs[(sub +  8) * FIN + k] * w;
        acc3 += Hs[(sub + 12) * FIN + k] * w;
    }
    float accs[4] = {acc0, acc1, acc2, acc3};
    #pragma unroll
    for (int q = 0; q < 4; ++q) {
        int i = i0 + sub + 4 * q;
        float a = accs[q];
        Wh[(size_t)i * FOUT + f] = a;
        float v1 = a * a1f, v2 = a * a2f;
        #pragma unroll
        for (int o = 32; o > 0; o >>= 1) {
            v1 += __shfl_xor(v1, o);
            v2 += __shfl_xor(v2, o);
        }
        if (f == 0) {
            float s = v1 + ab[0];
            float t = v2;
            s_src[i] = s; t_tar[i] = t;
            E1[i] = __expf(s); E2[i] = __expf(0.01f * s);
            PP[2 * i]     = __expf(t);
            PP[2 * i + 1] = __expf(0.01f * t);
        }
    }
}

// kA: rank (blocks 0..255, 8 nodes/wave) + A-stream denom via dynamic units.
// NO inter-block synchronization: rank outputs (sorted_idx/kidx) and denom are
// only read by LATER kernels (kernel-boundary coherence). Rank work hides under
// the 268 MB A-stream that the other 768 blocks start immediately.
__global__ __launch_bounds__(256, 4) void kA_rank_denom(
    const int* __restrict__ A,
    const float* __restrict__ t_tar, const float* __restrict__ s_src,
    const float* __restrict__ PP,
    const float* __restrict__ E1, const float* __restrict__ E2,
    int* __restrict__ sorted_idx, int* __restrict__ kidx,
    float* __restrict__ denom, unsigned* __restrict__ ctrs)
{
    __shared__ float Ts[NN];
    __shared__ float red[4][8][2];
    __shared__ unsigned ucur;
    int tid = threadIdx.x, wv = tid >> 6, lane = tid & 63;
    int b = blockIdx.x;

    if (b < NRANK) {
        const float4* tv = (const float4*)t_tar;
        float4* Tsv = (float4*)Ts;
        for (int idx = tid; idx < NN / 4; idx += 256) Tsv[idx] = tv[idx];
        __syncthreads();
        int g0 = b * 32 + wv * 8;
        float tj[8], thr[8];
        int rk[8], kc[8];
        #pragma unroll
        for (int q = 0; q < 8; ++q) {
            tj[q] = Ts[g0 + q];
            thr[q] = -s_src[g0 + q];
            rk[q] = 0; kc[q] = 0;
        }
        for (int k = lane; k < NN; k += 64) {
            float tk = Ts[k];
            #pragma unroll
            for (int q = 0; q < 8; ++q) {
                rk[q] += (tk < tj[q] || (tk == tj[q] && k < g0 + q)) ? 1 : 0;
                kc[q] += (tk < thr[q]) ? 1 : 0;
            }
        }
        #pragma unroll
        for (int q = 0; q < 8; ++q) {
            #pragma unroll
            for (int o = 32; o > 0; o >>= 1) {
                rk[q] += __shfl_xor(rk[q], o);
                kc[q] += __shfl_xor(kc[q], o);
            }
        }
        if (lane == 0) {
            #pragma unroll
            for (int q = 0; q < 8; ++q) {
                sorted_idx[rk[q]] = g0 + q;
                kidx[g0 + q] = kc[q];
            }
        }
    }

    // ---------- A-stream denom: dynamic 8-row units ----------
    for (;;) {
        if (tid == 0) ucur = atomicAdd(&ctrs[0], 1u);
        __syncthreads();
        unsigned u = ucur;
        __syncthreads();
        if (u >= NUNITS) break;
        int i0 = (int)u * 8;
        float e1r[8], accA[8], accB[8];
        #pragma unroll
        for (int r = 0; r < 8; ++r) { e1r[r] = E1[i0 + r]; accA[r] = 0.f; accB[r] = 0.f; }
        const float4* PPv = (const float4*)PP;
        for (int jv = tid; jv < NN / 4; jv += 256) {
            float4 ppA = PPv[2 * jv];
            float4 ppB = PPv[2 * jv + 1];
            #pragma unroll
            for (int r = 0; r < 8; ++r) {
                const iv4 a4 = __builtin_nontemporal_load(
                    (const iv4*)(A + (size_t)(i0 + r) * NN + jv * 4));
                float e1 = e1r[r];
                {
                    bool c = e1 * ppA.x >= 1.0f;
                    float af = (float)a4.x;
                    accA[r] += af * (c ? ppA.x : 0.0f);
                    accB[r] += af * (c ? 0.0f : ppA.y);
                }
                {
                    bool c = e1 * ppA.z >= 1.0f;
                    float af = (float)a4.y;
                    accA[r] += af * (c ? ppA.z : 0.0f);
                    accB[r] += af * (c ? 0.0f : ppA.w);
                }
                {
                    bool c = e1 * ppB.x >= 1.0f;
                    float af = (float)a4.z;
                    accA[r] += af * (c ? ppB.x : 0.0f);
                    accB[r] += af * (c ? 0.0f : ppB.y);
                }
                {
                    bool c = e1 * ppB.z >= 1.0f;
                    float af = (float)a4.w;
                    accA[r] += af * (c ? ppB.z : 0.0f);
                    accB[r] += af * (c ? 0.0f : ppB.w);
                }
            }
        }
        #pragma unroll
        for (int r = 0; r < 8; ++r) {
            #pragma unroll
            for (int o = 32; o > 0; o >>= 1) {
                accA[r] += __shfl_xor(accA[r], o);
                accB[r] += __shfl_xor(accB[r], o);
            }
        }
        if ((tid & 63) == 0) {
            #pragma unroll
            for (int r = 0; r < 8; ++r) { red[wv][r][0] = accA[r]; red[wv][r][1] = accB[r]; }
        }
        __syncthreads();
        if (tid < 8) {
            float sA = red[0][tid][0] + red[1][tid][0] + red[2][tid][0] + red[3][tid][0];
            float sB = red[0][tid][1] + red[1][tid][1] + red[2][tid][1] + red[3][tid][1];
            denom[i0 + tid] = E1[i0 + tid] * sA + E2[i0 + tid] * sB;
        }
        __syncthreads();
    }
}

// K3 phase A: per-chunk (32 m's) totals of v1 = P1*Wh and v2 = P2*Wh in sorted order.
__global__ __launch_bounds__(64) void k3a_tots(
    const float* __restrict__ Wh, const float* __restrict__ PP,
    const int* __restrict__ sorted_idx,
    float* __restrict__ tots1, float* __restrict__ tots2)
{
    int c = blockIdx.x, f = threadIdx.x;
    float t1 = 0.f, t2 = 0.f;
    int m0 = c * 32;
    #pragma unroll 8
    for (int m = m0; m < m0 + 32; ++m) {
        int sj = sorted_idx[m];
        float wh = Wh[(size_t)sj * 64 + f];
        t1 += PP[2 * sj]     * wh;
        t2 += PP[2 * sj + 1] * wh;
    }
    tots1[c * 64 + f] = t1; tots2[c * 64 + f] = t2;
}

// K3 phase BC fused: per-block offsets (linear sums over chunk totals) + emit.
__global__ __launch_bounds__(64) void k3bc_emit(
    const float* __restrict__ Wh, const float* __restrict__ PP,
    const int* __restrict__ sorted_idx,
    const float* __restrict__ tots1, const float* __restrict__ tots2,
    float* __restrict__ pre2, float* __restrict__ suf1)
{
    int c = blockIdx.x, f = threadIdx.x;
    float o2 = 0.f;
    #pragma unroll 8
    for (int w = 0; w < c; ++w) o2 += tots2[w * 64 + f];
    float o1 = 0.f;
    #pragma unroll 8
    for (int w = c + 1; w < 256; ++w) o1 += tots1[w * 64 + f];
    int m0 = c * 32;
    float whr[32], p1r[32], p2r[32];
    #pragma unroll
    for (int q = 0; q < 32; ++q) {
        int sj = sorted_idx[m0 + q];
        whr[q] = Wh[(size_t)sj * 64 + f];
        p1r[q] = PP[2 * sj]; p2r[q] = PP[2 * sj + 1];
    }
    float run2 = o2;
    #pragma unroll
    for (int q = 0; q < 32; ++q) {
        pre2[(size_t)(m0 + q) * 64 + f] = run2;
        run2 += p2r[q] * whr[q];
    }
    if (c == 255) pre2[(size_t)NN * 64 + f] = run2;   // full prefix total
    float run1 = o1;
    #pragma unroll
    for (int q = 31; q >= 0; --q) {
        run1 += p1r[q] * whr[q];
        suf1[(size_t)(m0 + q) * 64 + f] = run1;
    }
    if (c == 255) suf1[(size_t)NN * 64 + f] = 0.f;
}

// K5: out[i][f] = sigmoid( (E1_i*suf1[k_i][f] + E2_i*pre2[k_i][f]) / denom[i] )
__global__ __launch_bounds__(256) void k5_out(
    const float* __restrict__ suf1, const float* __restrict__ pre2,
    const int* __restrict__ kidx, const float* __restrict__ E1,
    const float* __restrict__ E2, const float* __restrict__ denom,
    float* __restrict__ out)
{
    int tid = threadIdx.x;
    int f = tid & 63, sub = tid >> 6;
    int i = blockIdx.x * 4 + sub;
    int k = kidx[i];
    float num = E1[i] * suf1[(size_t)k * 64 + f] + E2[i] * pre2[(size_t)k * 64 + f];
    float x = num / denom[i];
    out[(size_t)i * 64 + f] = 1.0f / (1.0f + __expf(-x));
}

extern "C" void kernel_launch(void* const* d_in, const int* in_sizes, int n_in,
                              void* d_out, int out_size, void* d_ws, size_t ws_size,
                              hipStream_t stream) {
    const float* H  = (const float*)d_in[0];
    const int*   A  = (const int*)d_in[1];
    const float* W  = (const float*)d_in[2];
    const float* bW = (const float*)d_in[3];
    const float* aw = (const float*)d_in[4];
    const float* ab = (const float*)d_in[5];
    float* out = (float*)d_out;

    float* ws    = (float*)d_ws;
    float* Wh    = ws;                    // 524288
    float* s_src = Wh + 524288;           // 8192
    float* t_tar = s_src + 8192;          // 8192
    float* E1    = t_tar + 8192;          // 8192
    float* E2    = E1 + 8192;             // 8192
    float* PP    = E2 + 8192;             // 16384
    float* pre2  = PP + 16384;            // 524352 ((N+1)*64)
    float* suf1  = pre2 + 524352;         // 524352
    float* tots1 = suf1 + 524352;         // 16384 (256*64)
    float* tots2 = tots1 + 16384;         // 16384
    float* denom = tots2 + 16384;         // 8192
    int* sorted_idx = (int*)(denom + 8192);   // 8192 ints
    int* kidx       = sorted_idx + 8192;      // 8192 ints
    unsigned* ctrs  = (unsigned*)(kidx + 8192); // 4 uints

    hipLaunchKernelGGL(k1_proj, dim3(512), dim3(256), 0, stream,
                       H, W, bW, aw, ab, Wh, s_src, t_tar, E1, E2, PP, ctrs);
    hipLaunchKernelGGL(kA_rank_denom, dim3(NBLK), dim3(256), 0, stream,
                       A, t_tar, s_src, PP, E1, E2, sorted_idx, kidx, denom, ctrs);
    hipLaunchKernelGGL(k3a_tots, dim3(256), dim3(64), 0, stream,
                       Wh, PP, sorted_idx, tots1, tots2);
    hipLaunchKernelGGL(k3bc_emit, dim3(256), dim3(64), 0, stream,
                       Wh, PP, sorted_idx, tots1, tots2, pre2, suf1);
    hipLaunchKernelGGL(k5_out, dim3(2048), dim3(256), 0, stream,
                       suf1, pre2, kidx, E1, E2, denom, out);
}